// Round 1
// baseline (31696.402 us; speedup 1.0000x reference)
//
#include <hip/hip_runtime.h>
#include <cstddef>

#define B_DIM 32
#define T_DIM 1000
#define I_DIM 3
#define R_DIM 2048
#define O_DIM 3

// ---------------------------------------------------------------------------
// Per-timestep kernel.
// grid = 256 blocks (8 reservoir rows each), block = 256 threads = 4 waves.
// wave w handles batches b = w*8 .. w*8+7 (all 32 batches covered).
// Lane-level K split: lane owns float4 at k = kc*256 + lane*4 (8 chunks).
// Register tile: 8 rows x 8 batches per lane -> 16 ds_read_b128 per 256 FMA.
// End of step: keep-half butterfly reduce (63 shuffles) so lane L owns output
// (r = L>>3, b_local = L&7); add input/noise term, tanh, store to states.
// ---------------------------------------------------------------------------
__global__ __launch_bounds__(256) void esn_step(
    const float* __restrict__ x,      // [B][T][I]
    const float* __restrict__ Win,    // [R][I]
    const float* __restrict__ Wres,   // [R][R]
    const float* __restrict__ noise,  // [B][R]
    float* __restrict__ states,      // [B][T][R]
    int t)
{
  __shared__ float Schunk[32][256];
  __shared__ float Wchunk[8][256];

  const int tid = threadIdx.x;
  const int blk = blockIdx.x;
  const int r0 = blk * 8;
  const int wv = tid >> 6;       // wave id 0..3
  const int lane = tid & 63;
  const int bbase = wv * 8;

  float acc[64];
#pragma unroll
  for (int i = 0; i < 64; ++i) acc[i] = 0.f;

  if (t > 0) {
#pragma unroll 1
    for (int kc = 0; kc < 8; ++kc) {
      const int k0 = kc * 256;
      // stage state chunk: 32 b x 256 k = 2048 float4, 8 per thread (coalesced)
#pragma unroll
      for (int j = 0; j < 8; ++j) {
        const int f4 = tid + j * 256;          // 0..2047
        const int b = f4 >> 6;                 // 64 float4 per row
        const int k4 = (f4 & 63) * 4;
        const float4 v = *(const float4*)&states[((size_t)b * T_DIM + (t - 1)) * R_DIM + k0 + k4];
        *(float4*)&Schunk[b][k4] = v;
      }
      // stage W chunk: 8 rows x 256 k = 512 float4, 2 per thread
#pragma unroll
      for (int j = 0; j < 2; ++j) {
        const int f4 = tid + j * 256;          // 0..511
        const int r = f4 >> 6;
        const int k4 = (f4 & 63) * 4;
        *(float4*)&Wchunk[r][k4] = *(const float4*)&Wres[(size_t)(r0 + r) * R_DIM + k0 + k4];
      }
      __syncthreads();

      const int kl = lane * 4;
      float4 wf[8];
#pragma unroll
      for (int r = 0; r < 8; ++r) wf[r] = *(const float4*)&Wchunk[r][kl];
#pragma unroll
      for (int b = 0; b < 8; ++b) {
        const float4 sf = *(const float4*)&Schunk[bbase + b][kl];
#pragma unroll
        for (int r = 0; r < 8; ++r) {
          acc[r * 8 + b] += wf[r].x * sf.x + wf[r].y * sf.y
                          + wf[r].z * sf.z + wf[r].w * sf.w;
        }
      }
      __syncthreads();
    }
  }

  // ---- keep-half butterfly reduction: 64 partials -> lane L owns output o=L
  float a32[32], a16[16], a8[8], a4[4], a2[2], a1;
  {
    const bool h = (lane & 32) != 0;
#pragma unroll
    for (int i = 0; i < 32; ++i) {
      const float s = h ? acc[i] : acc[i + 32];
      const float k = h ? acc[i + 32] : acc[i];
      a32[i] = k + __shfl_xor(s, 32, 64);
    }
  }
  {
    const bool h = (lane & 16) != 0;
#pragma unroll
    for (int i = 0; i < 16; ++i) {
      const float s = h ? a32[i] : a32[i + 16];
      const float k = h ? a32[i + 16] : a32[i];
      a16[i] = k + __shfl_xor(s, 16, 64);
    }
  }
  {
    const bool h = (lane & 8) != 0;
#pragma unroll
    for (int i = 0; i < 8; ++i) {
      const float s = h ? a16[i] : a16[i + 8];
      const float k = h ? a16[i + 8] : a16[i];
      a8[i] = k + __shfl_xor(s, 8, 64);
    }
  }
  {
    const bool h = (lane & 4) != 0;
#pragma unroll
    for (int i = 0; i < 4; ++i) {
      const float s = h ? a8[i] : a8[i + 4];
      const float k = h ? a8[i + 4] : a8[i];
      a4[i] = k + __shfl_xor(s, 4, 64);
    }
  }
  {
    const bool h = (lane & 2) != 0;
#pragma unroll
    for (int i = 0; i < 2; ++i) {
      const float s = h ? a4[i] : a4[i + 2];
      const float k = h ? a4[i + 2] : a4[i];
      a2[i] = k + __shfl_xor(s, 2, 64);
    }
  }
  {
    const bool h = (lane & 1) != 0;
    const float s = h ? a2[0] : a2[1];
    const float k = h ? a2[1] : a2[0];
    a1 = k + __shfl_xor(s, 1, 64);
  }

  // lane L owns output (r = L>>3, b_local = L&7)
  const int r = lane >> 3;
  const int bl = lane & 7;
  const int b = bbase + bl;
  const int rr = r0 + r;

  const float* xp = &x[((size_t)b * T_DIM + t) * I_DIM];
  const float* wp = &Win[(size_t)rr * I_DIM];
  float ext = noise[(size_t)b * R_DIM + rr]
            + xp[0] * wp[0] + xp[1] * wp[1] + xp[2] * wp[2];

  const float val = tanhf(ext + a1);
  states[((size_t)b * T_DIM + t) * R_DIM + rr] = val;
}

// ---------------------------------------------------------------------------
// Final readout: outputs[b][o] = states[b][T-1][:] . Wout[o][:]
// one wave per (b,o) pair; 96 waves -> 24 blocks x 256 threads.
// ---------------------------------------------------------------------------
__global__ __launch_bounds__(256) void esn_out(
    const float* __restrict__ states,   // [B][T][R]
    const float* __restrict__ Wout,     // [O][R]
    float* __restrict__ out)            // [B][O]
{
  const int w = (int)((blockIdx.x * 256 + threadIdx.x) >> 6);
  const int lane = threadIdx.x & 63;
  if (w >= B_DIM * O_DIM) return;
  const int b = w / O_DIM;
  const int o = w % O_DIM;

  const float* sp = &states[((size_t)b * T_DIM + (T_DIM - 1)) * R_DIM];
  const float* wp = &Wout[(size_t)o * R_DIM];

  float acc = 0.f;
#pragma unroll
  for (int j = 0; j < 8; ++j) {
    const int rr = j * 256 + lane * 4;
    const float4 s = *(const float4*)&sp[rr];
    const float4 ww = *(const float4*)&wp[rr];
    acc += s.x * ww.x + s.y * ww.y + s.z * ww.z + s.w * ww.w;
  }
#pragma unroll
  for (int m = 32; m >= 1; m >>= 1) acc += __shfl_xor(acc, m, 64);
  if (lane == 0) out[(size_t)b * O_DIM + o] = acc;
}

extern "C" void kernel_launch(void* const* d_in, const int* in_sizes, int n_in,
                              void* d_out, int out_size, void* d_ws, size_t ws_size,
                              hipStream_t stream) {
  const float* x     = (const float*)d_in[0];   // [32,1000,3]
  const float* Win   = (const float*)d_in[1];   // [2048,3]
  const float* Wres  = (const float*)d_in[2];   // [2048,2048]
  const float* Wout  = (const float*)d_in[3];   // [3,2048]
  const float* noise = (const float*)d_in[4];   // [32,2048]

  float* out = (float*)d_out;                    // [32,3] then states
  float* states = out + B_DIM * O_DIM;           // [32,1000,2048]

  for (int t = 0; t < T_DIM; ++t) {
    esn_step<<<R_DIM / 8, 256, 0, stream>>>(x, Win, Wres, noise, states, t);
  }
  esn_out<<<(B_DIM * O_DIM * 64 + 255) / 256, 256, 0, stream>>>(states, Wout, out);
}

// Round 5
// 30960.059 us; speedup vs baseline: 1.0238x; 1.0238x over previous
//
#include <hip/hip_runtime.h>
#include <cstddef>

#define B_DIM 32
#define T_DIM 1000
#define I_DIM 3
#define R_DIM 2048
#define O_DIM 3
#define NBLK 256
#define ROWS 8          // reservoir rows per block
#define NTHR 512        // 8 waves: waves 0-3 = k-half 0, waves 4-7 = k-half 1
#define KC 128          // k-chunk width per half per iteration
#define NITER 8         // chunks per half (8*128 = 1024)

// Persistent kernel: all 1000 timesteps in one launch, custom grid barrier.
// 256 blocks (1/CU, co-resident by construction: 41KB LDS, <=256 VGPR via
// launch_bounds), 512 threads. Each block owns 8 reservoir rows x 32 batches.
// State stores are agent-scope (LLC-visible); every step reads FRESH addresses
// (states[t-1]) so no stale-cache hazard; Wres stays L2-warm across steps.
__global__ __launch_bounds__(NTHR, 2) void esn_persist(
    const float* __restrict__ x,      // [B][T][I]
    const float* __restrict__ Win,    // [R][I]
    const float* __restrict__ Wres,   // [R][R]
    const float* __restrict__ Wout,   // [O][R]
    const float* __restrict__ noise,  // [B][R]
    float* __restrict__ states,       // [B][T][R]
    float* __restrict__ out,          // [B][O]
    int* __restrict__ flags)          // [NBLK] in ws (poison 0xAA = negative)
{
  __shared__ float Sc[2][32][KC];     // 32 KB  (state chunk per k-half)
  __shared__ float Wc[2][ROWS][KC];   // 8 KB   (W chunk per k-half)
  __shared__ float cross[4][64];      // 1 KB   (half-combine)

  const int tid  = threadIdx.x;
  const int blk  = blockIdx.x;
  const int r0   = blk * ROWS;
  const int h    = tid >> 8;          // k-half 0/1
  const int tl   = tid & 255;         // local id within half
  const int wv   = tid >> 6;          // wave 0..7
  const int wv4  = wv & 3;
  const int lane = tid & 63;
  const int bbase = wv4 * 8;

  // butterfly output mapping: lane L -> (row offset L>>3, batch bbase+(L&7))
  const int orow = lane >> 3;
  const int ob   = bbase + (lane & 7);
  const int orr  = r0 + orow;

  // t-invariant ext-term pieces (h==0 lanes produce outputs)
  float w0 = 0.f, w1 = 0.f, w2 = 0.f, nz = 0.f;
  if (h == 0) {
    w0 = Win[orr * I_DIM + 0];
    w1 = Win[orr * I_DIM + 1];
    w2 = Win[orr * I_DIM + 2];
    nz = noise[(size_t)ob * R_DIM + orr];
  }

#define ISSUE(kc, RS, RW)                                                      \
  {                                                                            \
    const int k0 = h * 1024 + (kc) * KC;                                       \
    _Pragma("unroll")                                                          \
    for (int j = 0; j < 4; ++j) {                                              \
      const int f  = tl + j * 256;                                             \
      const int bb = f >> 5;                                                   \
      const int k4 = (f & 31) * 4;                                             \
      RS[j] = *(const float4*)&states[((size_t)bb * T_DIM + (t - 1)) * R_DIM + \
                                      k0 + k4];                                \
    }                                                                          \
    {                                                                          \
      const int rr2 = tl >> 5;                                                 \
      const int k4  = (tl & 31) * 4;                                           \
      RW = *(const float4*)&Wres[(size_t)(r0 + rr2) * R_DIM + k0 + k4];        \
    }                                                                          \
  }

#define WRITE(RS, RW)                                                          \
  {                                                                            \
    _Pragma("unroll")                                                          \
    for (int j = 0; j < 4; ++j) {                                              \
      const int f  = tl + j * 256;                                             \
      const int bb = f >> 5;                                                   \
      const int k4 = (f & 31) * 4;                                             \
      *(float4*)&Sc[h][bb][k4] = RS[j];                                        \
    }                                                                          \
    {                                                                          \
      const int rr2 = tl >> 5;                                                 \
      const int k4  = (tl & 31) * 4;                                           \
      *(float4*)&Wc[h][rr2][k4] = RW;                                          \
    }                                                                          \
  }

#define COMPUTE()                                                              \
  {                                                                            \
    const int kl = lane * 2;                                                   \
    float2 wf[8];                                                              \
    _Pragma("unroll")                                                          \
    for (int r = 0; r < 8; ++r) wf[r] = *(const float2*)&Wc[h][r][kl];         \
    _Pragma("unroll")                                                          \
    for (int b = 0; b < 8; ++b) {                                              \
      const float2 sf = *(const float2*)&Sc[h][bbase + b][kl];                 \
      _Pragma("unroll")                                                        \
      for (int r = 0; r < 8; ++r)                                              \
        acc[r * 8 + b] += wf[r].x * sf.x + wf[r].y * sf.y;                     \
    }                                                                          \
  }

  for (int t = 0; t < T_DIM; ++t) {
    // issue per-step input loads early (latency hides under the k-loop)
    float x0 = 0.f, x1 = 0.f, x2 = 0.f;
    if (h == 0) {
      const float* xp = &x[((size_t)ob * T_DIM + t) * I_DIM];
      x0 = xp[0]; x1 = xp[1]; x2 = xp[2];
    }

    float acc[64];
#pragma unroll
    for (int i = 0; i < 64; ++i) acc[i] = 0.f;

    if (t > 0) {
      float4 rsA[4], rwA, rsB[4], rwB;
      ISSUE(0, rsA, rwA);
      ISSUE(1, rsB, rwB);
#pragma unroll 1
      for (int kc2 = 0; kc2 < NITER / 2; ++kc2) {
        __syncthreads();                 // prior compute done -> LDS reusable
        WRITE(rsA, rwA);
        __syncthreads();
        if (kc2 * 2 + 2 < NITER) ISSUE(kc2 * 2 + 2, rsA, rwA);
        COMPUTE();                       // chunk 2*kc2
        __syncthreads();
        WRITE(rsB, rwB);
        __syncthreads();
        if (kc2 * 2 + 3 < NITER) ISSUE(kc2 * 2 + 3, rsB, rwB);
        COMPUTE();                       // chunk 2*kc2+1
      }
    }

    // ---- keep-half butterfly: 64 partials -> lane L owns output L
    float a1;
    {
      float a32[32], a16[16], a8[8], a4[4], a2[2];
      {
        const bool hh = (lane & 32) != 0;
#pragma unroll
        for (int i = 0; i < 32; ++i) {
          const float s = hh ? acc[i] : acc[i + 32];
          const float k = hh ? acc[i + 32] : acc[i];
          a32[i] = k + __shfl_xor(s, 32, 64);
        }
      }
      {
        const bool hh = (lane & 16) != 0;
#pragma unroll
        for (int i = 0; i < 16; ++i) {
          const float s = hh ? a32[i] : a32[i + 16];
          const float k = hh ? a32[i + 16] : a32[i];
          a16[i] = k + __shfl_xor(s, 16, 64);
        }
      }
      {
        const bool hh = (lane & 8) != 0;
#pragma unroll
        for (int i = 0; i < 8; ++i) {
          const float s = hh ? a16[i] : a16[i + 8];
          const float k = hh ? a16[i + 8] : a16[i];
          a8[i] = k + __shfl_xor(s, 8, 64);
        }
      }
      {
        const bool hh = (lane & 4) != 0;
#pragma unroll
        for (int i = 0; i < 4; ++i) {
          const float s = hh ? a8[i] : a8[i + 4];
          const float k = hh ? a8[i + 4] : a8[i];
          a4[i] = k + __shfl_xor(s, 4, 64);
        }
      }
      {
        const bool hh = (lane & 2) != 0;
#pragma unroll
        for (int i = 0; i < 2; ++i) {
          const float s = hh ? a4[i] : a4[i + 2];
          const float k = hh ? a4[i + 2] : a4[i];
          a2[i] = k + __shfl_xor(s, 2, 64);
        }
      }
      {
        const bool hh = (lane & 1) != 0;
        const float s = hh ? a2[0] : a2[1];
        const float k = hh ? a2[1] : a2[0];
        a1 = k + __shfl_xor(s, 1, 64);
      }
    }

    // ---- combine k-halves, activation, agent-scope store
    if (h == 1) cross[wv4][lane] = a1;
    __syncthreads();
    if (h == 0) {
      const float tot = a1 + cross[wv4][lane];
      const float val = tanhf(x0 * w0 + x1 * w1 + x2 * w2 + nz + tot);
      __hip_atomic_store(&states[((size_t)ob * T_DIM + t) * R_DIM + orr], val,
                         __ATOMIC_RELAXED, __HIP_MEMORY_SCOPE_AGENT);
    }
    __syncthreads();  // per-wave vmcnt drained before barrier -> stores done

    // ---- grid barrier: flag release + spin on all 256 flags
    if (tid == 0)
      __hip_atomic_store(&flags[blk], t + 1, __ATOMIC_RELEASE,
                         __HIP_MEMORY_SCOPE_AGENT);
    if (wv == 0) {
      const int target = t + 1;
      int guard = 0;
      for (;;) {
        const int v0 = __hip_atomic_load(&flags[lane], __ATOMIC_RELAXED,
                                         __HIP_MEMORY_SCOPE_AGENT);
        const int v1 = __hip_atomic_load(&flags[lane + 64], __ATOMIC_RELAXED,
                                         __HIP_MEMORY_SCOPE_AGENT);
        const int v2 = __hip_atomic_load(&flags[lane + 128], __ATOMIC_RELAXED,
                                         __HIP_MEMORY_SCOPE_AGENT);
        const int v3 = __hip_atomic_load(&flags[lane + 192], __ATOMIC_RELAXED,
                                         __HIP_MEMORY_SCOPE_AGENT);
        const bool ok =
            (v0 >= target) && (v1 >= target) && (v2 >= target) && (v3 >= target);
        if (__all(ok)) break;
        if (++guard > (1 << 22)) break;  // deadlock escape (never in practice)
        __builtin_amdgcn_s_sleep(1);
      }
    }
    __builtin_amdgcn_fence(__ATOMIC_ACQUIRE, "workgroup");  // compiler fence
    __syncthreads();
  }

  // ---- readout: outputs[b][o] = states[b][T-1][:] . Wout[o][:]
  if (blk == 0) {
#pragma unroll 1
    for (int pi = 0; pi < 12; ++pi) {
      const int p = wv * 12 + pi;      // 8 waves x 12 = 96 pairs
      const int b = p / 3, o = p % 3;
      const float* sp = &states[((size_t)b * T_DIM + (T_DIM - 1)) * R_DIM];
      const float* wp = &Wout[(size_t)o * R_DIM];
      float a = 0.f;
#pragma unroll
      for (int j = 0; j < 8; ++j) {
        const int rr = j * 256 + lane * 4;
        const float4 s = *(const float4*)&sp[rr];
        const float4 w = *(const float4*)&wp[rr];
        a += s.x * w.x + s.y * w.y + s.z * w.z + s.w * w.w;
      }
#pragma unroll
      for (int m = 32; m >= 1; m >>= 1) a += __shfl_xor(a, m, 64);
      if (lane == 0) out[(size_t)b * O_DIM + o] = a;
    }
  }
}

extern "C" void kernel_launch(void* const* d_in, const int* in_sizes, int n_in,
                              void* d_out, int out_size, void* d_ws, size_t ws_size,
                              hipStream_t stream) {
  const float* x     = (const float*)d_in[0];
  const float* Win   = (const float*)d_in[1];
  const float* Wres  = (const float*)d_in[2];
  const float* Wout  = (const float*)d_in[3];
  const float* noise = (const float*)d_in[4];

  float* out    = (float*)d_out;              // [32,3]
  float* states = out + B_DIM * O_DIM;        // [32,1000,2048]
  int* flags    = (int*)d_ws;                 // [256], poison 0xAA < 1 (signed)

  esn_persist<<<NBLK, NTHR, 0, stream>>>(x, Win, Wres, Wout, noise,
                                         states, out, flags);
}

// Round 7
// 18469.661 us; speedup vs baseline: 1.7161x; 1.6763x over previous
//
#include <hip/hip_runtime.h>
#include <cstddef>

#define B_DIM 32
#define T_DIM 1000
#define I_DIM 3
#define R_DIM 2048
#define O_DIM 3
#define NBLK 256
#define ROWS 8          // reservoir rows per block
#define NTHR 512        // 8 waves: waves 0-3 = k-half 0, waves 4-7 = k-half 1
#define KCH 128         // k per chunk (lane*2 within chunk)
#define NCH 8           // chunks per half (8*128 = 1024)

// Persistent kernel, round 6.
// vs round 5 (31.1ms, WRITE_SIZE 39.8GB = spill scratch flushed by per-step
// agent-RELEASE buffer_wbl2):
//   - no LDS staging, no float4 staging arrays: S and W read direct-global
//     (coalesced 512B/row; L2-resident across the 32 blocks of each XCD)
//   - butterfly reduction in-place on acc[] (no a32[32] stacked live range)
//   - flag store is RELAXED sc1 (no wbl2); ordering via __syncthreads'
//     built-in s_waitcnt vmcnt(0) which retires all sc1 state stores at LLC
//     before any wave passes the barrier.
__global__ __launch_bounds__(NTHR, 2) void esn_persist(
    const float* __restrict__ x,      // [B][T][I]
    const float* __restrict__ Win,    // [R][I]
    const float* __restrict__ Wres,   // [R][R]
    const float* __restrict__ Wout,   // [O][R]
    const float* __restrict__ noise,  // [B][R]
    float* __restrict__ states,       // [B][T][R]
    float* __restrict__ out,          // [B][O]
    int* __restrict__ flags)          // [NBLK] in ws (poison 0xAA = negative)
{
  __shared__ float cross[4][64];      // k-half combine (1 KB)

  const int tid   = threadIdx.x;
  const int blk   = blockIdx.x;
  const int r0    = blk * ROWS;
  const int h     = tid >> 8;         // k-half 0/1
  const int wv    = tid >> 6;         // wave 0..7
  const int wv4   = wv & 3;
  const int lane  = tid & 63;
  const int bbase = wv4 * 8;

  // output mapping: lane L -> (batch = bbase + (L>>3), row = r0 + (L&7))
  // -> 8 consecutive lanes store 32 contiguous bytes.
  const int ob  = bbase + (lane >> 3);
  const int orr = r0 + (lane & 7);

  // t-invariant ext-term pieces (h==0 lanes produce outputs)
  float w0 = 0.f, w1 = 0.f, w2 = 0.f, nz = 0.f;
  if (h == 0) {
    w0 = Win[orr * I_DIM + 0];
    w1 = Win[orr * I_DIM + 1];
    w2 = Win[orr * I_DIM + 2];
    nz = noise[(size_t)ob * R_DIM + orr];
  }

  // per-lane k base within this half; per-row/batch base pointers (registers,
  // always indexed by compile-time constants in unrolled loops)
  const int klb = h * 1024 + lane * 2;
  const float* wp[8];
  const float* sp0[8];
#pragma unroll
  for (int r = 0; r < 8; ++r) wp[r] = Wres + (size_t)(r0 + r) * R_DIM + klb;
#pragma unroll
  for (int j = 0; j < 8; ++j)
    sp0[j] = states + (size_t)(bbase + j) * T_DIM * R_DIM + klb;

#define LOADC(kc, SF, WF)                                                      \
  {                                                                            \
    _Pragma("unroll")                                                          \
    for (int j = 0; j < 8; ++j)                                                \
      SF[j] = *(const float2*)(sp0[j] + soff + (kc) * KCH);                    \
    _Pragma("unroll")                                                          \
    for (int r = 0; r < 8; ++r)                                                \
      WF[r] = *(const float2*)(wp[r] + (kc) * KCH);                            \
  }

#define FMAC(SF, WF)                                                           \
  {                                                                            \
    _Pragma("unroll")                                                          \
    for (int j = 0; j < 8; ++j) {                                              \
      _Pragma("unroll")                                                        \
      for (int r = 0; r < 8; ++r)                                              \
        acc[j * 8 + r] += WF[r].x * SF[j].x + WF[r].y * SF[j].y;               \
    }                                                                          \
  }

#pragma unroll 1
  for (int t = 0; t < T_DIM; ++t) {
    // per-step input loads issued early (latency hides under the k-loop)
    float x0 = 0.f, x1 = 0.f, x2 = 0.f;
    if (h == 0) {
      const float* xp = &x[((size_t)ob * T_DIM + t) * I_DIM];
      x0 = xp[0]; x1 = xp[1]; x2 = xp[2];
    }

    float acc[64];
#pragma unroll
    for (int i = 0; i < 64; ++i) acc[i] = 0.f;

    if (t > 0) {
      const size_t soff = (size_t)(t - 1) * R_DIM;
      float2 sA[8], wA[8], sB[8], wB[8];
      LOADC(0, sA, wA);
#pragma unroll
      for (int kc = 0; kc < NCH; kc += 2) {
        LOADC(kc + 1, sB, wB);              // prefetch odd chunk
        FMAC(sA, wA);                       // compute even chunk
        if (kc + 2 < NCH) LOADC(kc + 2, sA, wA);
        FMAC(sB, wB);                       // compute odd chunk
      }
    }

    // ---- in-place keep-half butterfly: acc[0] = lane L's output L total
#pragma unroll
    for (int m = 32; m >= 1; m >>= 1) {
#pragma unroll
      for (int i = 0; i < m; ++i) {
        const bool hh = (lane & m) != 0;
        const float mine = hh ? acc[i] : acc[i + m];
        const float keep = hh ? acc[i + m] : acc[i];
        acc[i] = keep + __shfl_xor(mine, m, 64);
      }
    }

    // ---- combine k-halves, activation, sc1 store (LLC-visible)
    if (h == 1) cross[wv4][lane] = acc[0];
    __syncthreads();
    if (h == 0) {
      const float val =
          tanhf(x0 * w0 + x1 * w1 + x2 * w2 + nz + acc[0] + cross[wv4][lane]);
      __hip_atomic_store(&states[((size_t)ob * T_DIM + t) * R_DIM + orr], val,
                         __ATOMIC_RELAXED, __HIP_MEMORY_SCOPE_AGENT);
    }
    // barrier's built-in s_waitcnt vmcnt(0) retires every wave's sc1 stores
    // at the LLC before any wave proceeds -> release ordering without wbl2.
    __syncthreads();

    // ---- grid barrier: RELAXED flag release + spin on all 256 flags
    if (tid == 0)
      __hip_atomic_store(&flags[blk], t + 1, __ATOMIC_RELAXED,
                         __HIP_MEMORY_SCOPE_AGENT);
    if (wv == 0 && (t + 1 < T_DIM || blk == 0)) {
      const int target = t + 1;
      int guard = 0;
      for (;;) {
        const int v0 = __hip_atomic_load(&flags[lane], __ATOMIC_RELAXED,
                                         __HIP_MEMORY_SCOPE_AGENT);
        const int v1 = __hip_atomic_load(&flags[lane + 64], __ATOMIC_RELAXED,
                                         __HIP_MEMORY_SCOPE_AGENT);
        const int v2 = __hip_atomic_load(&flags[lane + 128], __ATOMIC_RELAXED,
                                         __HIP_MEMORY_SCOPE_AGENT);
        const int v3 = __hip_atomic_load(&flags[lane + 192], __ATOMIC_RELAXED,
                                         __HIP_MEMORY_SCOPE_AGENT);
        const bool ok =
            (v0 >= target) && (v1 >= target) && (v2 >= target) && (v3 >= target);
        if (__all(ok)) break;
        if (++guard > (1 << 22)) break;  // deadlock escape (never in practice)
        __builtin_amdgcn_s_sleep(1);
      }
    }
    __builtin_amdgcn_fence(__ATOMIC_ACQUIRE, "workgroup");  // compiler fence
    __syncthreads();
  }

  // ---- readout: outputs[b][o] = states[b][T-1][:] . Wout[o][:]
  if (blk == 0) {
#pragma unroll 1
    for (int pi = 0; pi < 12; ++pi) {
      const int p = wv * 12 + pi;      // 8 waves x 12 = 96 pairs
      const int b = p / 3, o = p % 3;
      const float* sp = &states[((size_t)b * T_DIM + (T_DIM - 1)) * R_DIM];
      const float* wq = &Wout[(size_t)o * R_DIM];
      float a = 0.f;
#pragma unroll
      for (int j = 0; j < 8; ++j) {
        const int rr = j * 256 + lane * 4;
        const float4 s = *(const float4*)&sp[rr];
        const float4 w = *(const float4*)&wq[rr];
        a += s.x * w.x + s.y * w.y + s.z * w.z + s.w * w.w;
      }
#pragma unroll
      for (int m = 32; m >= 1; m >>= 1) a += __shfl_xor(a, m, 64);
      if (lane == 0) out[(size_t)b * O_DIM + o] = a;
    }
  }
}

extern "C" void kernel_launch(void* const* d_in, const int* in_sizes, int n_in,
                              void* d_out, int out_size, void* d_ws, size_t ws_size,
                              hipStream_t stream) {
  const float* x     = (const float*)d_in[0];
  const float* Win   = (const float*)d_in[1];
  const float* Wres  = (const float*)d_in[2];
  const float* Wout  = (const float*)d_in[3];
  const float* noise = (const float*)d_in[4];

  float* out    = (float*)d_out;              // [32,3]
  float* states = out + B_DIM * O_DIM;        // [32,1000,2048]
  int* flags    = (int*)d_ws;                 // [256], poison 0xAA < 1 (signed)

  esn_persist<<<NBLK, NTHR, 0, stream>>>(x, Win, Wres, Wout, noise,
                                         states, out, flags);
}